// Round 5
// baseline (94.652 us; speedup 1.0000x reference)
//
#include <hip/hip_runtime.h>
#include <hip/hip_bf16.h>
#include <hip/hip_fp16.h>
#include <stdint.h>

typedef __attribute__((ext_vector_type(8))) _Float16 f16x8;
typedef __attribute__((ext_vector_type(4))) _Float16 f16x4;
typedef __attribute__((ext_vector_type(4))) float f32x4;
typedef __attribute__((ext_vector_type(4))) int i32x4;

#define GLD_LDS16(g, l) __builtin_amdgcn_global_load_lds( \
    (const __attribute__((address_space(1))) uint32_t*)(g), \
    (__attribute__((address_space(3))) uint32_t*)(l), 16, 0, 0)

// ---------------- W fp32 -> fp16 (into workspace), 512x2048 -------------
__global__ __launch_bounds__(256) void k_cvt_w(const float* __restrict__ W,
                                               _Float16* __restrict__ Wh) {
  int i = (blockIdx.x * 256 + threadIdx.x) * 8;  // 1048576 elems total
  float4 a = *(const float4*)(W + i);
  float4 b = *(const float4*)(W + i + 4);
  union { _Float16 h[8]; i32x4 v; } u;
  u.h[0] = (_Float16)a.x; u.h[1] = (_Float16)a.y;
  u.h[2] = (_Float16)a.z; u.h[3] = (_Float16)a.w;
  u.h[4] = (_Float16)b.x; u.h[5] = (_Float16)b.y;
  u.h[6] = (_Float16)b.z; u.h[7] = (_Float16)b.w;
  *(i32x4*)(Wh + i) = u.v;
}

__device__ inline float softplus_f(float x) {
  float e = __expf(-fabsf(x));
  return fmaxf(x, 0.f) + __logf(1.f + e);
}

// ---- fused GEMM(fp16x2-split MFMA) + softplus-diff partial ----
// Block 64 rows x 256 hid cols, BK=32, 64 K-steps. 8 waves 2Mx4N.
// T3+T4: raw s_barrier + counted vmcnt(3); loads have 2 iterations in
// flight (>= HBM latency). A: reg->cvt-once->LDS hi/lo (x2 buf).
// B: gld_lds pre-swizzled source (x3 buf, prefetch distance 2).
__global__ __launch_bounds__(512, 4) void k_main(
    const float* __restrict__ X,      // [16384][2048]
    const _Float16* __restrict__ Wh,  // [512][2048]
    const float* __restrict__ U,      // [512][2]
    const float* __restrict__ hb,     // [512]
    float* __restrict__ Dp) {         // [2][16384] partial logit-diffs
  __shared__ __align__(16) _Float16 AhS[2][64 * 32];   // 2 x 4 KB
  __shared__ __align__(16) _Float16 AlS[2][64 * 32];   // 2 x 4 KB
  __shared__ __align__(16) _Float16 BsS[3][256 * 32];  // 3 x 16 KB
  __shared__ float sD[64];

  const int t = threadIdx.x;
  const int lane = t & 63;
  const int wid = t >> 6;   // 0..7
  const int wm = wid >> 2;  // 0..1 (M half)
  const int wn = wid & 3;   // 0..3 (N quarter)
  const int bx = blockIdx.x;
  const int bm0 = (bx >> 1) * 64;
  const int nhalf = bx & 1;
  const int bn0 = nhalf * 256;
  const int lrow = lane & 15, lq = lane >> 4;

  if (t < 64) sD[t] = 0.f;

  f32x4 acc[2][4];
#pragma unroll
  for (int m = 0; m < 2; ++m)
#pragma unroll
    for (int n = 0; n < 4; ++n) acc[m][n] = (f32x4){0.f, 0.f, 0.f, 0.f};

  // A staging: thread -> row t>>3, float4 chunk t&7; swizzled ds_write
  // (validated R4): byte = (row*64 + 16*((c>>1)^(row&7))) + 8*(c&1).
  const int ar = t >> 3, ac = t & 7;
  const float* xsrc = X + (size_t)(bm0 + ar) * 2048 + ac * 4;
  const int awoff =
      (((ar * 64) + ((ac >> 1) << 4)) ^ ((ar & 7) << 4)) + (ac & 1) * 8;

  // B staging source permutation (validated R4): phys slot p holds logical
  // i = p ^ (p>>2) ^ (p>>4) within each 512B group.
  const int pp = lane & 31;
  const int ii = pp ^ (pp >> 2) ^ (pp >> 4);
  const int brow = wid * 32 + (lane >> 5) * 8 + (ii >> 2);
  const _Float16* bsrc = Wh + (size_t)(bn0 + brow) * 2048 + (ii & 3) * 8;

  char* bdst[3] = {(char*)&BsS[0][0] + wid * 2048,
                   (char*)&BsS[1][0] + wid * 2048,
                   (char*)&BsS[2][0] + wid * 2048};

  f32x4 araw[3];

  // ---- prologue: A(0); G(-2)={A(1),B(0)}; G(-1)={A(2),B(1)} ----
  araw[0] = *(const f32x4*)(xsrc);
  araw[1] = *(const f32x4*)(xsrc + 32);
  GLD_LDS16(bsrc, bdst[0]);
  GLD_LDS16(bsrc + 16 * 2048, bdst[0] + 1024);
  araw[2] = *(const f32x4*)(xsrc + 64);
  GLD_LDS16(bsrc + 32, bdst[1]);
  GLD_LDS16(bsrc + 32 + 16 * 2048, bdst[1] + 1024);
  asm volatile("s_waitcnt vmcnt(6)" ::: "memory");
  {
    f16x4 hv, lv;
#pragma unroll
    for (int j = 0; j < 4; ++j) {
      float v = araw[0][j];
      _Float16 hj = (_Float16)v;
      hv[j] = hj;
      lv[j] = (_Float16)(v - (float)hj);
    }
    *(f16x4*)((char*)&AhS[0][0] + awoff) = hv;
    *(f16x4*)((char*)&AlS[0][0] + awoff) = lv;
  }

  // Body: RA=A-reg ring write slot, RC=A-reg ring cvt slot, AW/AR=A-LDS
  // write/read slot, BW/BR=B-LDS write/read slot, KA/KB=A/B tile indices.
#define BODY(RA, RC, AW, AR, BW, BR, KA, KB) do {                          \
    asm volatile("s_waitcnt vmcnt(3) lgkmcnt(0)" ::: "memory");            \
    __builtin_amdgcn_s_barrier();                                          \
    __builtin_amdgcn_sched_barrier(0);                                     \
    araw[RA] = *(const f32x4*)(xsrc + (size_t)(KA) * 32);                  \
    GLD_LDS16(bsrc + (size_t)(KB) * 32, bdst[BW]);                         \
    GLD_LDS16(bsrc + (size_t)(KB) * 32 + 16 * 2048, bdst[BW] + 1024);      \
    {                                                                      \
      f16x4 hv, lv;                                                        \
      _Pragma("unroll") for (int j = 0; j < 4; ++j) {                      \
        float v = araw[RC][j];                                             \
        _Float16 hj = (_Float16)v;                                         \
        hv[j] = hj;                                                        \
        lv[j] = (_Float16)(v - (float)hj);                                 \
      }                                                                    \
      *(f16x4*)((char*)&AhS[AW][0] + awoff) = hv;                          \
      *(f16x4*)((char*)&AlS[AW][0] + awoff) = lv;                          \
    }                                                                      \
    {                                                                      \
      f16x8 fah[2], fal[2], fbf[4];                                        \
      _Pragma("unroll") for (int mf = 0; mf < 2; ++mf) {                   \
        int row = wm * 32 + mf * 16 + lrow;                                \
        int off = (row * 64 + lq * 16) ^ ((row & 7) << 4);                 \
        fah[mf] = *(const f16x8*)((const char*)&AhS[AR][0] + off);         \
        fal[mf] = *(const f16x8*)((const char*)&AlS[AR][0] + off);         \
      }                                                                    \
      _Pragma("unroll") for (int nf = 0; nf < 4; ++nf) {                   \
        int row = wn * 64 + nf * 16 + lrow;                                \
        int off = (row * 64 + lq * 16) ^ ((row & 7) << 4);                 \
        fbf[nf] = *(const f16x8*)((const char*)&BsS[BR][0] + off);         \
      }                                                                    \
      __builtin_amdgcn_s_setprio(1);                                       \
      _Pragma("unroll") for (int mf = 0; mf < 2; ++mf)                     \
        _Pragma("unroll") for (int nf = 0; nf < 4; ++nf) {                 \
          acc[mf][nf] = __builtin_amdgcn_mfma_f32_16x16x32_f16(            \
              fah[mf], fbf[nf], acc[mf][nf], 0, 0, 0);                     \
          acc[mf][nf] = __builtin_amdgcn_mfma_f32_16x16x32_f16(            \
              fal[mf], fbf[nf], acc[mf][nf], 0, 0, 0);                     \
        }                                                                  \
      __builtin_amdgcn_s_setprio(0);                                       \
    }                                                                      \
  } while (0)

  // main loop: t = tb+i, i=0..5 (period-6 slot pattern), t in [0,60)
  for (int tb = 0; tb < 60; tb += 6) {
    BODY(0, 1, 1, 0, 2, 0, tb + 3, tb + 2);
    BODY(1, 2, 0, 1, 0, 1, tb + 4, tb + 3);
    BODY(2, 0, 1, 0, 1, 2, tb + 5, tb + 4);
    BODY(0, 1, 0, 1, 2, 0, tb + 6, tb + 5);
    BODY(1, 2, 1, 0, 0, 1, tb + 7, tb + 6);
    BODY(2, 0, 0, 1, 1, 2, tb + 8, tb + 7);
  }
  // peeled t=60..63 (KA/KB clamped to 63; dup prefetches land in unread slots)
  BODY(0, 1, 1, 0, 2, 0, 63, 62);
  BODY(1, 2, 0, 1, 0, 1, 63, 63);
  BODY(2, 0, 1, 0, 1, 2, 63, 63);
  BODY(0, 1, 0, 1, 2, 0, 63, 63);
#undef BODY

  // ---- epilogue: softplus-difference partial for this N-half ----
  // acc[mf][nf][r]: row = bm0 + wm*32 + mf*16 + lq*4 + r
  //                 col = bn0 + wn*64 + nf*16 + lrow
  float dpart[8];
#pragma unroll
  for (int i = 0; i < 8; ++i) dpart[i] = 0.f;
#pragma unroll
  for (int nf = 0; nf < 4; ++nf) {
    int h = bn0 + wn * 64 + nf * 16 + lrow;
    float hbv = hb[h];
    float u0 = U[2 * h], u1 = U[2 * h + 1];
#pragma unroll
    for (int mf = 0; mf < 2; ++mf)
#pragma unroll
      for (int r = 0; r < 4; ++r) {
        float pf = acc[mf][nf][r] + hbv;
        dpart[mf * 4 + r] += softplus_f(pf + u0) - softplus_f(pf + u1);
      }
  }
#pragma unroll
  for (int i = 0; i < 8; ++i) {
    float v = dpart[i];
    v += __shfl_xor(v, 1);
    v += __shfl_xor(v, 2);
    v += __shfl_xor(v, 4);
    v += __shfl_xor(v, 8);
    dpart[i] = v;
  }
  if (lrow == 0) {
#pragma unroll
    for (int mf = 0; mf < 2; ++mf)
#pragma unroll
      for (int r = 0; r < 4; ++r)
        atomicAdd(&sD[wm * 32 + mf * 16 + lq * 4 + r], dpart[mf * 4 + r]);
  }
  __syncthreads();
  if (t < 64) Dp[nhalf * 16384 + bm0 + t] = sD[t];
}

// ---- combine the two N-half partials + sigmoid ----
__global__ __launch_bounds__(256) void k_final(const float* __restrict__ Dp,
                                               const float* __restrict__ yb,
                                               float* __restrict__ out) {
  int i = blockIdx.x * 256 + threadIdx.x;  // 0..16383
  float D = Dp[i] + Dp[16384 + i] + yb[0] - yb[1];  // logit0 - logit1
  float e = __expf(-D);
  float o0 = 1.f / (1.f + e);
  float o1 = e * o0;
  *(float2*)(out + (size_t)i * 2) = make_float2(o0, o1);
}

extern "C" void kernel_launch(void* const* d_in, const int* in_sizes, int n_in,
                              void* d_out, int out_size, void* d_ws,
                              size_t ws_size, hipStream_t stream) {
  const float* X = (const float*)d_in[0];
  const float* W = (const float*)d_in[1];
  const float* U = (const float*)d_in[2];
  const float* hb = (const float*)d_in[3];
  const float* yb = (const float*)d_in[4];
  float* out = (float*)d_out;
  _Float16* Wh = (_Float16*)d_ws;                       // 2 MB
  float* Dp = (float*)((char*)d_ws + 2 * 1024 * 1024);  // 128 KB partials

  hipLaunchKernelGGL(k_cvt_w, dim3(512), dim3(256), 0, stream, W, Wh);
  hipLaunchKernelGGL(k_main, dim3(512), dim3(512), 0, stream, X, Wh, U, hb, Dp);
  hipLaunchKernelGGL(k_final, dim3(64), dim3(256), 0, stream, Dp, yb, out);
}

// Round 6
// 91.894 us; speedup vs baseline: 1.0300x; 1.0300x over previous
//
#include <hip/hip_runtime.h>
#include <hip/hip_bf16.h>
#include <hip/hip_fp16.h>
#include <stdint.h>

typedef __attribute__((ext_vector_type(8))) _Float16 f16x8;
typedef __attribute__((ext_vector_type(4))) _Float16 f16x4;
typedef __attribute__((ext_vector_type(4))) float f32x4;
typedef __attribute__((ext_vector_type(4))) int i32x4;

#define GLD_LDS16(g, l) __builtin_amdgcn_global_load_lds( \
    (const __attribute__((address_space(1))) uint32_t*)(g), \
    (__attribute__((address_space(3))) uint32_t*)(l), 16, 0, 0)

// ---------------- W fp32 -> fp16 (into workspace), 512x2048 -------------
__global__ __launch_bounds__(256) void k_cvt_w(const float* __restrict__ W,
                                               _Float16* __restrict__ Wh) {
  int i = (blockIdx.x * 256 + threadIdx.x) * 8;  // 1048576 elems total
  float4 a = *(const float4*)(W + i);
  float4 b = *(const float4*)(W + i + 4);
  union { _Float16 h[8]; i32x4 v; } u;
  u.h[0] = (_Float16)a.x; u.h[1] = (_Float16)a.y;
  u.h[2] = (_Float16)a.z; u.h[3] = (_Float16)a.w;
  u.h[4] = (_Float16)b.x; u.h[5] = (_Float16)b.y;
  u.h[6] = (_Float16)b.z; u.h[7] = (_Float16)b.w;
  *(i32x4*)(Wh + i) = u.v;
}

__device__ inline float softplus_f(float x) {
  float e = __expf(-fabsf(x));
  return fmaxf(x, 0.f) + __logf(1.f + e);
}

// ---- fused GEMM(fp16 MFMA) + softplus-diff partial ----
// Block 64 rows x 256 hid cols, BK=32, 64 K-steps, 8 waves 2Mx4N.
// Pipeline per iter t: {gld B(t+2); load A(t+4); cvt+write A(t+2);
// frag ds_reads for t+1; MFMA on frags(t); vmcnt(1) lgkmcnt(0); s_barrier}.
// ds_reads overlap the MFMA cluster (m201 phase pattern); global loads
// keep 2-4 iterations of flight; never vmcnt(0) in the loop.
__global__ __launch_bounds__(512, 4) void k_main(
    const float* __restrict__ X,      // [16384][2048]
    const _Float16* __restrict__ Wh,  // [512][2048]
    const float* __restrict__ U,      // [512][2]
    const float* __restrict__ hb,     // [512]
    float* __restrict__ Dp) {         // [2][16384] partial logit-diffs
  __shared__ __align__(16) _Float16 AhS[2][64 * 32];   // 2 x 4 KB
  __shared__ __align__(16) _Float16 BsS[3][256 * 32];  // 3 x 16 KB
  __shared__ float sD[64];

  const int t = threadIdx.x;
  const int lane = t & 63;
  const int wid = t >> 6;   // 0..7
  const int wm = wid >> 2;  // 0..1 (M half)
  const int wn = wid & 3;   // 0..3 (N quarter)
  const int bx = blockIdx.x;
  const int bm0 = (bx >> 1) * 64;
  const int nhalf = bx & 1;
  const int bn0 = nhalf * 256;
  const int lrow = lane & 15, lq = lane >> 4;

  if (t < 64) sD[t] = 0.f;

  f32x4 acc[2][4];
#pragma unroll
  for (int m = 0; m < 2; ++m)
#pragma unroll
    for (int n = 0; n < 4; ++n) acc[m][n] = (f32x4){0.f, 0.f, 0.f, 0.f};

  // A staging (validated R4/R5): thread -> row t>>3, float4 chunk t&7;
  // swizzled ds_write byte = (row*64 + 16*((c>>1)^(row&7)...)) per formula.
  const int ar = t >> 3, ac = t & 7;
  const float* xsrc = X + (size_t)(bm0 + ar) * 2048 + ac * 4;
  const int awoff =
      (((ar * 64) + ((ac >> 1) << 4)) ^ ((ar & 7) << 4)) + (ac & 1) * 8;

  // B staging source permutation (validated R4/R5): phys slot p holds
  // logical i = p ^ (p>>2) ^ (p>>4) within each 512B group.
  const int pp = lane & 31;
  const int ii = pp ^ (pp >> 2) ^ (pp >> 4);
  const int brow = wid * 32 + (lane >> 5) * 8 + (ii >> 2);
  const _Float16* bsrc = Wh + (size_t)(bn0 + brow) * 2048 + (ii & 3) * 8;

  char* bdst[3] = {(char*)&BsS[0][0] + wid * 2048,
                   (char*)&BsS[1][0] + wid * 2048,
                   (char*)&BsS[2][0] + wid * 2048};

  f32x4 araw[3];        // A(k) lives in slot k%3
  f16x8 fA[2][2], fB[2][4];  // frag double-buffer (set = tile&1)

#define CVT_A(SL, AB) do {                                                 \
    f16x4 hv;                                                              \
    _Pragma("unroll") for (int j = 0; j < 4; ++j)                          \
      hv[j] = (_Float16)araw[SL][j];                                       \
    *(f16x4*)((char*)&AhS[AB][0] + awoff) = hv;                            \
  } while (0)

  // ---- prologue ----
  GLD_LDS16(bsrc, bdst[0]);
  GLD_LDS16(bsrc + 16 * 2048, bdst[0] + 1024);
  GLD_LDS16(bsrc + 32, bdst[1]);
  GLD_LDS16(bsrc + 32 + 16 * 2048, bdst[1] + 1024);
  araw[0] = *(const f32x4*)(xsrc);           // A(0)
  araw[1] = *(const f32x4*)(xsrc + 32);      // A(1)
  araw[2] = *(const f32x4*)(xsrc + 64);      // A(2)
  asm volatile("s_waitcnt vmcnt(2)" ::: "memory");  // B0,B1,A0 done
  CVT_A(0, 0);                               // A(0) -> Abuf[0]
  asm volatile("s_waitcnt vmcnt(1)" ::: "memory");  // A1 done
  CVT_A(1, 1);                               // A(1) -> Abuf[1]
  araw[0] = *(const f32x4*)(xsrc + 96);      // A(3) -> slot 0
  asm volatile("s_waitcnt vmcnt(1) lgkmcnt(0)" ::: "memory");  // A2 done
  __builtin_amdgcn_s_barrier();
  // frag set 0 <- tile 0 (Abuf[0], Bbuf[0])
#pragma unroll
  for (int mf = 0; mf < 2; ++mf) {
    int row = wm * 32 + mf * 16 + lrow;
    int off = (row * 64 + lq * 16) ^ ((row & 7) << 4);
    fA[0][mf] = *(const f16x8*)((const char*)&AhS[0][0] + off);
  }
#pragma unroll
  for (int nf = 0; nf < 4; ++nf) {
    int row = wn * 64 + nf * 16 + lrow;
    int off = (row * 64 + lq * 16) ^ ((row & 7) << 4);
    fB[0][nf] = *(const f16x8*)((const char*)&BsS[0][0] + off);
  }

  // SLA=A-load slot (t+1)%3 for A(t+4); SCV=cvt slot (t+2)%3; AWB=t&1 write
  // buf; ARB=(t+1)&1 read buf; BW=(t+2)%3; BR=(t+1)%3; FC=t&1; FL=(t+1)&1.
#define BODY(SLA, SCV, AWB, ARB, BW, BR, FC, FL, KA, KB) do {              \
    GLD_LDS16(bsrc + (size_t)(KB) * 32, bdst[BW]);                         \
    GLD_LDS16(bsrc + (size_t)(KB) * 32 + 16 * 2048, bdst[BW] + 1024);      \
    araw[SLA] = *(const f32x4*)(xsrc + (size_t)(KA) * 32);                 \
    CVT_A(SCV, AWB);                                                       \
    _Pragma("unroll") for (int mf = 0; mf < 2; ++mf) {                     \
      int row = wm * 32 + mf * 16 + lrow;                                  \
      int off = (row * 64 + lq * 16) ^ ((row & 7) << 4);                   \
      fA[FL][mf] = *(const f16x8*)((const char*)&AhS[ARB][0] + off);       \
    }                                                                      \
    _Pragma("unroll") for (int nf = 0; nf < 4; ++nf) {                     \
      int row = wn * 64 + nf * 16 + lrow;                                  \
      int off = (row * 64 + lq * 16) ^ ((row & 7) << 4);                   \
      fB[FL][nf] = *(const f16x8*)((const char*)&BsS[BR][0] + off);        \
    }                                                                      \
    __builtin_amdgcn_sched_barrier(0);                                     \
    __builtin_amdgcn_s_setprio(1);                                         \
    _Pragma("unroll") for (int mf = 0; mf < 2; ++mf)                       \
      _Pragma("unroll") for (int nf = 0; nf < 4; ++nf)                     \
        acc[mf][nf] = __builtin_amdgcn_mfma_f32_16x16x32_f16(              \
            fA[FC][mf], fB[FC][nf], acc[mf][nf], 0, 0, 0);                 \
    __builtin_amdgcn_s_setprio(0);                                         \
    asm volatile("s_waitcnt vmcnt(1) lgkmcnt(0)" ::: "memory");            \
    __builtin_amdgcn_sched_barrier(0);                                     \
    __builtin_amdgcn_s_barrier();                                          \
  } while (0)

  // t = tb..tb+5, period-6 slot pattern; t in [0,60)
  for (int tb = 0; tb < 60; tb += 6) {
    BODY(1, 2, 0, 1, 2, 1, 0, 1, tb + 4, tb + 2);
    BODY(2, 0, 1, 0, 0, 2, 1, 0, tb + 5, tb + 3);
    BODY(0, 1, 0, 1, 1, 0, 0, 1, tb + 6, tb + 4);
    BODY(1, 2, 1, 0, 2, 1, 1, 0, tb + 7, tb + 5);
    BODY(2, 0, 0, 1, 0, 2, 0, 1, tb + 8, tb + 6);
    BODY(0, 1, 1, 0, 1, 0, 1, 0, tb + 9, tb + 7);
  }
  // peeled t=60..63 (prefetch indices clamped to 63; dups land unused)
  BODY(1, 2, 0, 1, 2, 1, 0, 1, 63, 62);
  BODY(2, 0, 1, 0, 0, 2, 1, 0, 63, 63);
  BODY(0, 1, 0, 1, 1, 0, 0, 1, 63, 63);
  BODY(1, 2, 1, 0, 2, 1, 1, 0, 63, 63);
#undef BODY
#undef CVT_A

  // ---- epilogue: softplus-difference partial for this N-half ----
  // acc[mf][nf][r]: row = bm0 + wm*32 + mf*16 + lq*4 + r
  //                 col = bn0 + wn*64 + nf*16 + lrow
  float dpart[8];
#pragma unroll
  for (int i = 0; i < 8; ++i) dpart[i] = 0.f;
#pragma unroll
  for (int nf = 0; nf < 4; ++nf) {
    int h = bn0 + wn * 64 + nf * 16 + lrow;
    float hbv = hb[h];
    float u0 = U[2 * h], u1 = U[2 * h + 1];
#pragma unroll
    for (int mf = 0; mf < 2; ++mf)
#pragma unroll
      for (int r = 0; r < 4; ++r) {
        float pf = acc[mf][nf][r] + hbv;
        dpart[mf * 4 + r] += softplus_f(pf + u0) - softplus_f(pf + u1);
      }
  }
#pragma unroll
  for (int i = 0; i < 8; ++i) {
    float v = dpart[i];
    v += __shfl_xor(v, 1);
    v += __shfl_xor(v, 2);
    v += __shfl_xor(v, 4);
    v += __shfl_xor(v, 8);
    dpart[i] = v;
  }
  if (lrow == 0) {
#pragma unroll
    for (int mf = 0; mf < 2; ++mf)
#pragma unroll
      for (int r = 0; r < 4; ++r)
        atomicAdd(&sD[wm * 32 + mf * 16 + lq * 4 + r], dpart[mf * 4 + r]);
  }
  __syncthreads();
  if (t < 64) Dp[nhalf * 16384 + bm0 + t] = sD[t];
}

// ---- combine the two N-half partials + sigmoid ----
__global__ __launch_bounds__(256) void k_final(const float* __restrict__ Dp,
                                               const float* __restrict__ yb,
                                               float* __restrict__ out) {
  int i = blockIdx.x * 256 + threadIdx.x;  // 0..16383
  float D = Dp[i] + Dp[16384 + i] + yb[0] - yb[1];  // logit0 - logit1
  float e = __expf(-D);
  float o0 = 1.f / (1.f + e);
  float o1 = e * o0;
  *(float2*)(out + (size_t)i * 2) = make_float2(o0, o1);
}

extern "C" void kernel_launch(void* const* d_in, const int* in_sizes, int n_in,
                              void* d_out, int out_size, void* d_ws,
                              size_t ws_size, hipStream_t stream) {
  const float* X = (const float*)d_in[0];
  const float* W = (const float*)d_in[1];
  const float* U = (const float*)d_in[2];
  const float* hb = (const float*)d_in[3];
  const float* yb = (const float*)d_in[4];
  float* out = (float*)d_out;
  _Float16* Wh = (_Float16*)d_ws;                       // 2 MB
  float* Dp = (float*)((char*)d_ws + 2 * 1024 * 1024);  // 128 KB partials

  hipLaunchKernelGGL(k_cvt_w, dim3(512), dim3(256), 0, stream, W, Wh);
  hipLaunchKernelGGL(k_main, dim3(512), dim3(512), 0, stream, X, Wh, U, hb, Dp);
  hipLaunchKernelGGL(k_final, dim3(64), dim3(256), 0, stream, Dp, yb, out);
}

// Round 7
// 78.918 us; speedup vs baseline: 1.1994x; 1.1644x over previous
//
#include <hip/hip_runtime.h>
#include <hip/hip_bf16.h>
#include <hip/hip_fp16.h>
#include <stdint.h>

typedef __attribute__((ext_vector_type(8))) _Float16 f16x8;
typedef __attribute__((ext_vector_type(4))) float f32x4;
typedef __attribute__((ext_vector_type(4))) int i32x4;

#define GLD_LDS16(g, l) __builtin_amdgcn_global_load_lds( \
    (const __attribute__((address_space(1))) uint32_t*)(g), \
    (__attribute__((address_space(3))) uint32_t*)(l), 16, 0, 0)

// ---------------- W fp32 -> fp16 (into workspace), 512x2048 -------------
__global__ __launch_bounds__(256) void k_cvt_w(const float* __restrict__ W,
                                               _Float16* __restrict__ Wh) {
  int i = (blockIdx.x * 256 + threadIdx.x) * 8;  // 1048576 elems total
  float4 a = *(const float4*)(W + i);
  float4 b = *(const float4*)(W + i + 4);
  union { _Float16 h[8]; i32x4 v; } u;
  u.h[0] = (_Float16)a.x; u.h[1] = (_Float16)a.y;
  u.h[2] = (_Float16)a.z; u.h[3] = (_Float16)a.w;
  u.h[4] = (_Float16)b.x; u.h[5] = (_Float16)b.y;
  u.h[6] = (_Float16)b.z; u.h[7] = (_Float16)b.w;
  *(i32x4*)(Wh + i) = u.v;
}

__device__ inline float softplus_f(float x) {
  float e = __expf(-fabsf(x));
  return fmaxf(x, 0.f) + __logf(1.f + e);
}

// ---- fused GEMM(fp16 MFMA) + softplus-diff + sigmoid, all-DMA staging ----
// Grid 256 (1 block/CU), block = 64 rows x 512 hid cols, BK=32, 64 steps.
// 8 waves 2Mx4N (wave-tile 32x128): 16 MFMA + 12 ds_read_b128 per step.
// A: fp32 via global_load_lds, 3 slots, prefetch dist 2 (cvt after ds_read).
// B: fp16 W-panels of k=64 via global_load_lds, 2 slots, staged every other
// step, consumed in two k-halves. Counted waits vmcnt(1)/vmcnt(9) alternate;
// never vmcnt(0) in the loop. Both LDS layouts: 128B rows, ^((row&7)<<4).
__global__ __launch_bounds__(512, 2) void k_main(
    const float* __restrict__ X,      // [16384][2048]
    const _Float16* __restrict__ Wh,  // [512][2048]
    const float* __restrict__ U,      // [512][2]
    const float* __restrict__ hb,     // [512]
    const float* __restrict__ yb,     // [2]
    float* __restrict__ out) {        // [16384][2]
  __shared__ __align__(16) float As[3][64 * 32];      // 3 x 8 KB
  __shared__ __align__(16) _Float16 Bs[2][512 * 64];  // 2 x 64 KB
  __shared__ float sD[64];

  const int t = threadIdx.x;
  const int lane = t & 63;
  const int wid = t >> 6;   // 0..7
  const int wm = wid >> 2;  // 0..1 (M half)
  const int wn = wid & 3;   // 0..3 (N quarter)
  const int bm0 = blockIdx.x * 64;
  const int lrow = lane & 15, lq = lane >> 4;
  const int r7 = lrow & 7;

  if (t < 64) sD[t] = 0.f;

  f32x4 acc[2][8];
#pragma unroll
  for (int m = 0; m < 2; ++m)
#pragma unroll
    for (int n = 0; n < 8; ++n) acc[m][n] = (f32x4){0.f, 0.f, 0.f, 0.f};

  // DMA source addresses (pre-swizzled global source; LDS dest linear).
  // Each gld_lds covers 8 rows x 128B; lane l -> row l>>3, phys slot l&7,
  // which holds logical 16B-chunk (l&7)^(l>>3)  [inverse of read-side XOR].
  const int l8 = lane >> 3, s8 = lane & 7;
  const int swz = s8 ^ l8;
  const float* asrc = X + (size_t)(bm0 + wid * 8 + l8) * 2048 + swz * 4;
  const _Float16* bsrc = Wh + (size_t)(wid * 64 + l8) * 2048 + swz * 8;

  char* const adst0 = (char*)&As[0][0] + wid * 1024;
  char* const adst1 = (char*)&As[1][0] + wid * 1024;
  char* const adst2 = (char*)&As[2][0] + wid * 1024;
  char* const bdst0 = (char*)&Bs[0][0] + wid * 8192;
  char* const bdst1 = (char*)&Bs[1][0] + wid * 8192;
  char* const adst[3] = {adst0, adst1, adst2};
  char* const bdstw[2] = {bdst0, bdst1};

  // A frag read swizzle (lane-constant): slots {lq*2, lq*2+1} ^ r7
  const int a_s0 = (lq * 2) ^ r7;
  const int a_s1 = a_s0 ^ 1;

#define STAGE_B(PB, SL) do {                                               \
    _Pragma("unroll") for (int i = 0; i < 8; ++i)                          \
      GLD_LDS16(bsrc + (size_t)(PB) * 64 + (size_t)i * 8 * 2048,           \
                bdstw[SL] + i * 1024);                                     \
  } while (0)

#define STAGE_A(KA, SL) GLD_LDS16(asrc + (size_t)(KA) * 32, adst[SL])

#define COMPUTE(AR, BR, HT) do {                                           \
    f16x8 fa[2]; f16x8 fb[8];                                              \
    _Pragma("unroll") for (int mf = 0; mf < 2; ++mf) {                     \
      const char* ab =                                                     \
          (const char*)&As[AR][0] + (wm * 32 + mf * 16 + lrow) * 128;      \
      f32x4 a0 = *(const f32x4*)(ab + a_s0 * 16);                          \
      f32x4 a1 = *(const f32x4*)(ab + a_s1 * 16);                          \
      _Pragma("unroll") for (int j = 0; j < 4; ++j) {                      \
        fa[mf][j] = (_Float16)a0[j];                                       \
        fa[mf][j + 4] = (_Float16)a1[j];                                   \
      }                                                                    \
    }                                                                      \
    const int sB = ((HT)*4 + lq) ^ r7;                                     \
    _Pragma("unroll") for (int nf = 0; nf < 8; ++nf) {                     \
      const char* bb = (const char*)&Bs[BR][0] +                           \
                       (wn * 128 + nf * 16 + lrow) * 128 + sB * 16;        \
      fb[nf] = *(const f16x8*)bb;                                          \
    }                                                                      \
    __builtin_amdgcn_s_setprio(1);                                         \
    _Pragma("unroll") for (int mf = 0; mf < 2; ++mf)                       \
      _Pragma("unroll") for (int nf = 0; nf < 8; ++nf)                     \
        acc[mf][nf] = __builtin_amdgcn_mfma_f32_16x16x32_f16(              \
            fa[mf], fb[nf], acc[mf][nf], 0, 0, 0);                         \
    __builtin_amdgcn_s_setprio(0);                                         \
  } while (0)

  // Even step: drain {B(P), A(2P)} -> vmcnt(1); stage B(P+1) + A(t+2).
#define BODY_E(AR, BR, HT, AW, BW, KA, PB) do {                            \
    asm volatile("s_waitcnt vmcnt(1)" ::: "memory");                       \
    __builtin_amdgcn_sched_barrier(0);                                     \
    __builtin_amdgcn_s_barrier();                                          \
    __builtin_amdgcn_sched_barrier(0);                                     \
    STAGE_B(PB, BW);                                                       \
    STAGE_A(KA, AW);                                                       \
    COMPUTE(AR, BR, HT);                                                   \
  } while (0)

  // Odd step: drain {A(2P+1)} -> vmcnt(9); stage A(t+2) only.
#define BODY_O(AR, BR, HT, AW, KA) do {                                    \
    asm volatile("s_waitcnt vmcnt(9)" ::: "memory");                       \
    __builtin_amdgcn_sched_barrier(0);                                     \
    __builtin_amdgcn_s_barrier();                                          \
    __builtin_amdgcn_sched_barrier(0);                                     \
    STAGE_A(KA, AW);                                                       \
    COMPUTE(AR, BR, HT);                                                   \
  } while (0)

  // ---- prologue: queue = [B0 x8, A0, A1]  (10 in flight) ----
  STAGE_B(0, 0);
  STAGE_A(0, 0);
  STAGE_A(1, 1);

  // ---- main loop: period-12 slot pattern (A%3, B-panel parity, k-half) ----
  for (int tb = 0; tb < 60; tb += 12) {
    const int P = tb >> 1;
    BODY_E(0, 0, 0, 2, 1, tb + 2, P + 1);
    BODY_O(1, 0, 1, 0, tb + 3);
    BODY_E(2, 1, 0, 1, 0, tb + 4, P + 2);
    BODY_O(0, 1, 1, 2, tb + 5);
    BODY_E(1, 0, 0, 0, 1, tb + 6, P + 3);
    BODY_O(2, 0, 1, 1, tb + 7);
    BODY_E(0, 1, 0, 2, 0, tb + 8, P + 4);
    BODY_O(1, 1, 1, 0, tb + 9);
    BODY_E(2, 0, 0, 1, 1, tb + 10, P + 5);
    BODY_O(0, 0, 1, 2, tb + 11);
    BODY_E(1, 1, 0, 0, 0, tb + 12, P + 6);
    BODY_O(2, 1, 1, 1, tb + 13);
  }
  // ---- peeled t=60..63 (issues clamped; dup data lands in unread slots) --
  BODY_E(0, 0, 0, 2, 1, 62, 31);
  BODY_O(1, 0, 1, 0, 63);
  BODY_E(2, 1, 0, 1, 0, 63, 31);
  BODY_O(0, 1, 1, 2, 63);
#undef BODY_E
#undef BODY_O
#undef COMPUTE
#undef STAGE_A
#undef STAGE_B

  // ---- epilogue: softplus-difference, per-row reduce, sigmoid ----
  // acc[mf][nf][r]: row = bm0 + wm*32 + mf*16 + lq*4 + r
  //                 col = wn*128 + nf*16 + lrow
  float dpart[8];
#pragma unroll
  for (int i = 0; i < 8; ++i) dpart[i] = 0.f;
#pragma unroll
  for (int nf = 0; nf < 8; ++nf) {
    int h = wn * 128 + nf * 16 + lrow;
    float hbv = hb[h];
    float u0 = U[2 * h], u1 = U[2 * h + 1];
#pragma unroll
    for (int mf = 0; mf < 2; ++mf)
#pragma unroll
      for (int r = 0; r < 4; ++r) {
        float pf = acc[mf][nf][r] + hbv;
        dpart[mf * 4 + r] += softplus_f(pf + u0) - softplus_f(pf + u1);
      }
  }
#pragma unroll
  for (int i = 0; i < 8; ++i) {
    float v = dpart[i];
    v += __shfl_xor(v, 1);
    v += __shfl_xor(v, 2);
    v += __shfl_xor(v, 4);
    v += __shfl_xor(v, 8);
    dpart[i] = v;
  }
  if (lrow == 0) {
#pragma unroll
    for (int mf = 0; mf < 2; ++mf)
#pragma unroll
      for (int r = 0; r < 4; ++r)
        atomicAdd(&sD[wm * 32 + mf * 16 + lq * 4 + r], dpart[mf * 4 + r]);
  }
  __syncthreads();
  if (t < 64) {
    float Dl = sD[t] + yb[0] - yb[1];  // logit0 - logit1
    float e = __expf(-Dl);
    float o0 = 1.f / (1.f + e);
    float o1 = e * o0;
    *(float2*)(out + (size_t)(bm0 + t) * 2) = make_float2(o0, o1);
  }
}

extern "C" void kernel_launch(void* const* d_in, const int* in_sizes, int n_in,
                              void* d_out, int out_size, void* d_ws,
                              size_t ws_size, hipStream_t stream) {
  const float* X = (const float*)d_in[0];
  const float* W = (const float*)d_in[1];
  const float* U = (const float*)d_in[2];
  const float* hb = (const float*)d_in[3];
  const float* yb = (const float*)d_in[4];
  float* out = (float*)d_out;
  _Float16* Wh = (_Float16*)d_ws;  // 2 MB scratch

  hipLaunchKernelGGL(k_cvt_w, dim3(512), dim3(256), 0, stream, W, Wh);
  hipLaunchKernelGGL(k_main, dim3(256), dim3(512), 0, stream, X, Wh, U, hb, yb,
                     out);
}